// Round 4
// baseline (276.221 us; speedup 1.0000x reference)
//
#include <hip/hip_runtime.h>
#include <hip/hip_bf16.h>

// GraphSAGE 3-layer forward, MI355X. Round 9:
//  - GEMM: full A-tile register prefetch. R8 had only 4 loads (1KB) in flight
//    per wave -> <4KB/CU outstanding vs ~21KB needed at 6TB/s x 900cy (Little's
//    law) -> 35us/GEMM at MfmaUtil 2.4%, hbm 800GB/s. Now ALL 16 A dwordx4
//    loads (4 rf x 4 ks) + 16 B loads issue before any MFMA: ~32KB in
//    flight/wave, 8 waves/CU. VGPR ~208 -> 2 waves/SIMD (self-hiding).
//    AF32 (layer 0) stages f32 in two rf-pair halves to cap VGPR (~230).
//  - everything else unchanged from R8 (vectorized gathers, CSR build, casts).

typedef __attribute__((ext_vector_type(8))) short bf16x8;
typedef __attribute__((ext_vector_type(4))) float f32x4;

#define NPB 128            // nodes per bucket (bucket = dst >> 7)
#define BCAP 2560          // per-bucket staging capacity (mean 2048, sd ~45)
#define EPB 8192           // edges per distribute block
#define EPT 32             // edges per thread (256 thr)
#define CPAD 16            // global counter stride in ints (64B line each)

__device__ __forceinline__ unsigned short f2bf(float f) {
    unsigned int u = __builtin_bit_cast(unsigned int, f);
    u += 0x7fffu + ((u >> 16) & 1u);           // round-to-nearest-even
    return (unsigned short)(u >> 16);
}
__device__ __forceinline__ float bf2f(unsigned int bits16) {
    return __builtin_bit_cast(float, bits16 << 16);
}
__device__ __forceinline__ bf16x8 pack8(float4 lo, float4 hi) {
    bf16x8 r;
    r[0] = (short)f2bf(lo.x); r[1] = (short)f2bf(lo.y);
    r[2] = (short)f2bf(lo.z); r[3] = (short)f2bf(lo.w);
    r[4] = (short)f2bf(hi.x); r[5] = (short)f2bf(hi.y);
    r[6] = (short)f2bf(hi.z); r[7] = (short)f2bf(hi.w);
    return r;
}

// ---------------- CSR phase A: block-staged distribute ----------------
// staging word: dst << 16 | src (both < 65536). bucket = word >> 23 (= dst>>7).

__global__ __launch_bounds__(256) void distribute_kernel(const int* __restrict__ dst,
                                                         const int* __restrict__ srcv,
                                                         int* __restrict__ gcnt,
                                                         unsigned int* __restrict__ staging,
                                                         int E, int NBc) {
    __shared__ unsigned int stage[EPB];      // bucket-sorted edges (32KB)
    __shared__ int hist[400];                // histogram, then LDS cursor
    __shared__ int lstart[400];              // exclusive prefix (incl. sentinel bucket)
    __shared__ int gbase[400];               // reserved global base per bucket
    __shared__ int scanbuf[256];
    int t = threadIdx.x;
    int e0 = blockIdx.x * EPB;
    unsigned int w[EPT];

    for (int b = t; b < NBc + 1; b += 256) hist[b] = 0;
    __syncthreads();

#pragma unroll
    for (int i = 0; i < EPT; ++i) {
        int e = e0 + i * 256 + t;            // coalesced
        unsigned int word = 0xFFFFFFFFu;     // sentinel -> bucket NBc
        if (e < E) word = ((unsigned int)dst[e] << 16) | (unsigned int)srcv[e];
        w[i] = word;
        int b = (int)(word >> 23); if (b > NBc) b = NBc;
        atomicAdd(&hist[b], 1);
    }
    __syncthreads();

    // exclusive scan over NBc+1 entries (2 per thread, Hillis-Steele on pairs)
    int b0 = 2 * t, b1 = 2 * t + 1;
    int h0 = (b0 <= NBc) ? hist[b0] : 0;
    int h1 = (b1 <= NBc) ? hist[b1] : 0;
    int pair = h0 + h1;
    scanbuf[t] = pair;
    __syncthreads();
    for (int off = 1; off < 256; off <<= 1) {
        int v = (t >= off) ? scanbuf[t - off] : 0;
        __syncthreads();
        scanbuf[t] += v;
        __syncthreads();
    }
    int excl = scanbuf[t] - pair;
    if (b0 <= NBc) lstart[b0] = excl;
    if (b1 <= NBc) lstart[b1] = excl + h0;
    __syncthreads();

    // one padded-line global atomic per non-empty bucket
    for (int b = t; b < NBc; b += 256) {
        int h = hist[b];
        gbase[b] = h ? atomicAdd(&gcnt[b * CPAD], h) : 0;
    }
    for (int b = t; b < NBc + 1; b += 256) hist[b] = lstart[b];   // -> LDS cursors
    __syncthreads();

#pragma unroll
    for (int i = 0; i < EPT; ++i) {
        unsigned int word = w[i];
        int b = (int)(word >> 23); if (b > NBc) b = NBc;
        int p = atomicAdd(&hist[b], 1);
        stage[p] = word;
    }
    __syncthreads();

    int total = lstart[NBc];                 // valid edges in this block
    for (int i = t; i < total; i += 256) {   // contiguous runs per bucket
        unsigned int word = stage[i];
        int b = (int)(word >> 23);
        int gpos = gbase[b] + (i - lstart[b]);
        staging[(size_t)b * BCAP + gpos] = word;
    }
}

// ---------------- CSR phase B: per-bucket local build (scan folded in) ----------------

__global__ __launch_bounds__(256) void build_kernel(const unsigned int* __restrict__ staging,
                                                    const int* __restrict__ gcnt,
                                                    int* __restrict__ row_ptr,
                                                    int* __restrict__ adj, int N, int NBc) {
    __shared__ int hist[NPB];   // histogram, then cursors
    __shared__ int scn[NPB];
    __shared__ int wsum[4];
    int b = blockIdx.x;
    int t = threadIdx.x;
    int n0 = b * NPB;
    int nb = N - n0; if (nb > NPB) nb = NPB;
    int ec = gcnt[b * CPAD];
    const unsigned int* st = staging + (size_t)b * BCAP;

    // exclusive bucket base: sum of gcnt[0..b)
    int a = 0;
    for (int j = t; j < b; j += 256) a += gcnt[j * CPAD];
#pragma unroll
    for (int off = 32; off; off >>= 1) a += __shfl_xor(a, off);
    if ((t & 63) == 0) wsum[t >> 6] = a;
    if (t < NPB) hist[t] = 0;
    __syncthreads();
    int bb = wsum[0] + wsum[1] + wsum[2] + wsum[3];

    for (int i = t; i < ec; i += 256)
        atomicAdd(&hist[(st[i] >> 16) & (NPB - 1)], 1);
    __syncthreads();

    int v = (t < NPB) ? hist[t] : 0;
    if (t < NPB) scn[t] = v;
    __syncthreads();
    for (int off = 1; off < NPB; off <<= 1) {
        int u = (t >= off && t < NPB) ? scn[t - off] : 0;
        __syncthreads();
        if (t < NPB) scn[t] += u;
        __syncthreads();
    }
    if (t < NPB) hist[t] = scn[t] - v;      // exclusive prefix -> cursor base
    if (t < nb) row_ptr[n0 + t] = bb + (scn[t] - v);
    if (b == NBc - 1 && t == 0) row_ptr[N] = bb + ec;   // total == E
    __syncthreads();

    for (int i = t; i < ec; i += 256) {
        unsigned int pk = st[i];
        int p = atomicAdd(&hist[(pk >> 16) & (NPB - 1)], 1);
        adj[bb + p] = (int)(pk & 0xffffu);
    }
}

// ---------------- weight casts: 6 tensors -> bf16 (x cast fused into GEMM0) ----------------

__global__ void cast_w_kernel(const float* p0, const float* p1, const float* p2,
                              const float* p3, const float* p4, const float* p5,
                              unsigned short* __restrict__ wbf) {
    int w = blockIdx.x * 256 + threadIdx.x;
    if (w < 40960) {
        const float* src;
        int local;
        if      (w < 8192)  { src = p0; local = w; }
        else if (w < 16384) { src = p1; local = w - 8192; }
        else if (w < 24576) { src = p2; local = w - 16384; }
        else if (w < 32768) { src = p3; local = w - 24576; }
        else if (w < 36864) { src = p4; local = w - 32768; }
        else                { src = p5; local = w - 36864; }
        float2 v = ((const float2*)src)[local];
        unsigned int p = (unsigned int)f2bf(v.x) | ((unsigned int)f2bf(v.y) << 16);
        ((unsigned int*)wbf)[w] = p;
    }
}

// ---------------- MFMA GEMM: full-tile register prefetch ----------------
// Block = 64 rows x (4*CF*16) cols; wave w owns col-group w (CF 16-col frags).
// All B (CF*4) and A (4*4) dwordx4 loads issue before any MFMA: ~32KB in
// flight per wave (Little's law at 6TB/s x ~900cy needs ~21KB/CU).
// AF32: A is f32 (layer 0, x); two rf-pair halves cap VGPR (~230).

template<int CF, int AF32>
__global__ __launch_bounds__(256) void gemm_mfma_kernel(const void* __restrict__ Hp,
                                                        const unsigned short* __restrict__ Wl,
                                                        const unsigned short* __restrict__ Wr,
                                                        unsigned short* __restrict__ C,
                                                        int N) {
    int wave = threadIdx.x >> 6;
    int lane = threadIdx.x & 63;
    int l15 = lane & 15, quad = lane >> 4;
    const int NCOL = 4 * CF * 16;          // 256 (layers 0/1) or 128 (layer 2)
    const int half = NCOL >> 1;
    int m0 = blockIdx.x * 64;

    // B fragments (loop-invariant, independent)
    bf16x8 bfr[CF][4];
#pragma unroll
    for (int cf = 0; cf < CF; ++cf) {
        int col0 = (wave * CF + cf) * 16;
        const unsigned short* W = (col0 < half) ? Wl : Wr;
        int wr = (col0 < half ? col0 : col0 - half) + l15;
#pragma unroll
        for (int ks = 0; ks < 4; ++ks)
            bfr[cf][ks] = ((const bf16x8*)(W + (size_t)wr * 128))[ks * 4 + quad];
    }

    f32x4 acc[4][CF] = {};

    if constexpr (AF32) {
        // two halves of the A tile (rf pairs), 16 f32x4 loads in flight each
#pragma unroll
        for (int h = 0; h < 2; ++h) {
            float4 fa[2][4][2];
#pragma unroll
            for (int p = 0; p < 2; ++p) {
                int rf = h * 2 + p;
                int r0 = m0 + rf * 16 + l15; if (r0 > N - 1) r0 = N - 1;
                const float4* A = (const float4*)((const float*)Hp + (size_t)r0 * 128);
#pragma unroll
                for (int ks = 0; ks < 4; ++ks) {
                    int vidx = ks * 4 + quad;
                    fa[p][ks][0] = A[vidx * 2];
                    fa[p][ks][1] = A[vidx * 2 + 1];
                }
            }
#pragma unroll
            for (int p = 0; p < 2; ++p) {
                int rf = h * 2 + p;
#pragma unroll
                for (int ks = 0; ks < 4; ++ks) {
                    bf16x8 a = pack8(fa[p][ks][0], fa[p][ks][1]);
#pragma unroll
                    for (int cf = 0; cf < CF; ++cf)
                        acc[rf][cf] = __builtin_amdgcn_mfma_f32_16x16x32_bf16(a, bfr[cf][ks],
                                                                              acc[rf][cf], 0, 0, 0);
                }
            }
        }
    } else {
        // full A tile prefetch: 16 independent dwordx4 loads
        bf16x8 afr[4][4];
#pragma unroll
        for (int rf = 0; rf < 4; ++rf) {
            int r0 = m0 + rf * 16 + l15; if (r0 > N - 1) r0 = N - 1;
            const bf16x8* A = (const bf16x8*)((const unsigned short*)Hp + (size_t)r0 * 128);
#pragma unroll
            for (int ks = 0; ks < 4; ++ks)
                afr[rf][ks] = A[ks * 4 + quad];
        }
#pragma unroll
        for (int rf = 0; rf < 4; ++rf)
#pragma unroll
            for (int ks = 0; ks < 4; ++ks)
#pragma unroll
                for (int cf = 0; cf < CF; ++cf)
                    acc[rf][cf] = __builtin_amdgcn_mfma_f32_16x16x32_bf16(afr[rf][ks], bfr[cf][ks],
                                                                          acc[rf][cf], 0, 0, 0);
    }

#pragma unroll
    for (int rf = 0; rf < 4; ++rf)
#pragma unroll
        for (int cf = 0; cf < CF; ++cf)
#pragma unroll
            for (int r = 0; r < 4; ++r) {
                int row = m0 + rf * 16 + quad * 4 + r;
                if (row < N)
                    C[(size_t)row * NCOL + (wave * CF + cf) * 16 + l15] = f2bf(acc[rf][cf][r]);
            }
}

// ---------------- Aggregation (layers 0,1): wave/node, vectorized 16B gathers ----
// lane = (g, c): g = lane>>4 edge slot (4 edges/round), c = lane&15 chunk
// (cols c*8..c*8+7). One dwordx4 load instruction = 4 rows x 256B = 1KB.

__global__ __launch_bounds__(256) void agg_relu_kernel(const unsigned short* __restrict__ C,
                                                       const int* __restrict__ row_ptr,
                                                       const int* __restrict__ adj,
                                                       const float* __restrict__ bias,
                                                       unsigned short* __restrict__ hout, int N) {
    int node = (int)((blockIdx.x * blockDim.x + threadIdx.x) >> 6);
    int lane = threadIdx.x & 63;
    if (node >= N) return;
    int g = lane >> 4;
    int c = lane & 15;
    int beg = row_ptr[node], end = row_ptr[node + 1];
    float p[8] = {};

    int e = beg;
    while (e < end) {
        int cnt = end - e; if (cnt > 64) cnt = 64;
        int ll = lane; if (ll > cnt - 1) ll = cnt - 1;
        int myidx = adj[e + ll];
        int c1 = cnt - 1;
        for (int i = 0; i < cnt; i += 16) {
            int t0 = i + g, t1 = i + 4 + g, t2 = i + 8 + g, t3 = i + 12 + g;
            int s0 = __shfl(myidx, t0 > c1 ? c1 : t0);
            int s1 = __shfl(myidx, t1 > c1 ? c1 : t1);
            int s2 = __shfl(myidx, t2 > c1 ? c1 : t2);
            int s3 = __shfl(myidx, t3 > c1 ? c1 : t3);
            float m0 = t0 < cnt ? 1.f : 0.f;
            float m1 = t1 < cnt ? 1.f : 0.f;
            float m2 = t2 < cnt ? 1.f : 0.f;
            float m3 = t3 < cnt ? 1.f : 0.f;
            bf16x8 v0 = ((const bf16x8*)(C + (size_t)s0 * 256))[c];
            bf16x8 v1 = ((const bf16x8*)(C + (size_t)s1 * 256))[c];
            bf16x8 v2 = ((const bf16x8*)(C + (size_t)s2 * 256))[c];
            bf16x8 v3 = ((const bf16x8*)(C + (size_t)s3 * 256))[c];
#pragma unroll
            for (int k = 0; k < 8; ++k) {
                p[k] += m0 * bf2f((unsigned short)v0[k]);
                p[k] += m1 * bf2f((unsigned short)v1[k]);
                p[k] += m2 * bf2f((unsigned short)v2[k]);
                p[k] += m3 * bf2f((unsigned short)v3[k]);
            }
        }
        e += cnt;
    }

    // reduce across the 4 edge-slot groups (lane bits 4,5)
#pragma unroll
    for (int k = 0; k < 8; ++k) {
        p[k] += __shfl_xor(p[k], 16);
        p[k] += __shfl_xor(p[k], 32);
    }

    int deg = end - beg;
    float inv = 1.0f / (float)(deg > 1 ? deg : 1);
    bf16x8 sv = ((const bf16x8*)(C + (size_t)node * 256))[16 + c];   // Wr self part
    float4 b0 = ((const float4*)bias)[2 * c];
    float4 b1 = ((const float4*)bias)[2 * c + 1];
    float bb[8] = {b0.x, b0.y, b0.z, b0.w, b1.x, b1.y, b1.z, b1.w};
    bf16x8 o;
#pragma unroll
    for (int k = 0; k < 8; ++k) {
        float v = fmaxf(p[k] * inv + bb[k] + bf2f((unsigned short)sv[k]), 0.f);
        o[k] = (short)f2bf(v);
    }
    if (g == 0)
        ((bf16x8*)(hout + (size_t)node * 128))[c] = o;
}

// ---------------- Final layer: vectorized gathers + fused log_softmax ----------------
// lane = (g, c): g = lane>>3 edge slot (8 edges/round), c = lane&7 chunk
// (cols c*8..c*8+7). Row = 64 cols bf16 = 128B = 8 chunks.

__global__ __launch_bounds__(256) void final_kernel(const unsigned short* __restrict__ C,
                                                    const int* __restrict__ row_ptr,
                                                    const int* __restrict__ adj,
                                                    const float* __restrict__ bias,
                                                    float* __restrict__ out, int N) {
    int node = (int)((blockIdx.x * blockDim.x + threadIdx.x) >> 6);
    int lane = threadIdx.x & 63;
    if (node >= N) return;
    int g = lane >> 3;
    int c = lane & 7;
    int beg = row_ptr[node], end = row_ptr[node + 1];
    float p[8] = {};

    int e = beg;
    while (e < end) {
        int cnt = end - e; if (cnt > 64) cnt = 64;
        int ll = lane; if (ll > cnt - 1) ll = cnt - 1;
        int myidx = adj[e + ll];
        int c1 = cnt - 1;
        for (int i = 0; i < cnt; i += 16) {
            int ta = i + g, tb = i + 8 + g;
            int sa = __shfl(myidx, ta > c1 ? c1 : ta);
            int sb = __shfl(myidx, tb > c1 ? c1 : tb);
            float ma = ta < cnt ? 1.f : 0.f;
            float mb = tb < cnt ? 1.f : 0.f;
            bf16x8 va = ((const bf16x8*)(C + (size_t)sa * 128))[c];
            bf16x8 vb = ((const bf16x8*)(C + (size_t)sb * 128))[c];
#pragma unroll
            for (int k = 0; k < 8; ++k) {
                p[k] += ma * bf2f((unsigned short)va[k]);
                p[k] += mb * bf2f((unsigned short)vb[k]);
            }
        }
        e += cnt;
    }

    // reduce across the 8 edge-slot groups (lane bits 3,4,5)
#pragma unroll
    for (int k = 0; k < 8; ++k) {
        p[k] += __shfl_xor(p[k], 8);
        p[k] += __shfl_xor(p[k], 16);
        p[k] += __shfl_xor(p[k], 32);
    }

    int deg = end - beg;
    float inv = 1.0f / (float)(deg > 1 ? deg : 1);
    bf16x8 sv = ((const bf16x8*)(C + (size_t)node * 128))[8 + c];    // Wr self part
    float4 b0 = ((const float4*)bias)[2 * c];
    float4 b1 = ((const float4*)bias)[2 * c + 1];
    float bb[8] = {b0.x, b0.y, b0.z, b0.w, b1.x, b1.y, b1.z, b1.w};
    float u[8];
#pragma unroll
    for (int k = 0; k < 8; ++k)
        u[k] = p[k] * inv + bb[k] + bf2f((unsigned short)sv[k]);

    // log_softmax over the 64 cols: per-lane max/sum over 8, then across c
    float m = u[0];
#pragma unroll
    for (int k = 1; k < 8; ++k) m = fmaxf(m, u[k]);
#pragma unroll
    for (int off = 1; off < 8; off <<= 1) m = fmaxf(m, __shfl_xor(m, off));
    float se = 0.f;
#pragma unroll
    for (int k = 0; k < 8; ++k) se += __expf(u[k] - m);
#pragma unroll
    for (int off = 1; off < 8; off <<= 1) se += __shfl_xor(se, off);
    float ls = __logf(se);

    if (g == 0) {
        float4 o0 = {u[0] - m - ls, u[1] - m - ls, u[2] - m - ls, u[3] - m - ls};
        float4 o1 = {u[4] - m - ls, u[5] - m - ls, u[6] - m - ls, u[7] - m - ls};
        ((float4*)(out + (size_t)node * 64))[2 * c] = o0;
        ((float4*)(out + (size_t)node * 64))[2 * c + 1] = o1;
    }
}

// ---------------- Launch ----------------

extern "C" void kernel_launch(void* const* d_in, const int* in_sizes, int n_in,
                              void* d_out, int out_size, void* d_ws, size_t ws_size,
                              hipStream_t stream) {
    const float* x   = (const float*)d_in[0];
    const int*   ei  = (const int*)d_in[1];
    const float* Wl0 = (const float*)d_in[2];
    const float* bl0 = (const float*)d_in[3];
    const float* Wr0 = (const float*)d_in[4];
    const float* Wl1 = (const float*)d_in[5];
    const float* bl1 = (const float*)d_in[6];
    const float* Wr1 = (const float*)d_in[7];
    const float* Wl2 = (const float*)d_in[8];
    const float* bl2 = (const float*)d_in[9];
    const float* Wr2 = (const float*)d_in[10];
    float* out = (float*)d_out;

    const int N  = in_sizes[0] / 128;   // 50000
    const int E  = in_sizes[1] / 2;     // 800000
    const int NB = (N + NPB - 1) / NPB; // 391 buckets

    char* ws = (char*)d_ws;
    auto alloc = [&](size_t bytes) {
        char* p = ws;
        ws += (bytes + 255) & ~(size_t)255;
        return p;
    };
    int*   row_ptr    = (int*)alloc((size_t)(N + 1) * 4);
    int*   adj        = (int*)alloc((size_t)E * 4);
    int*   gcnt       = (int*)alloc((size_t)NB * CPAD * 4);  // 64B-padded counters
    unsigned int* staging = (unsigned int*)alloc((size_t)NB * BCAP * 4);
    unsigned short* wbf = (unsigned short*)alloc((size_t)81920 * 2);
    unsigned short* C   = (unsigned short*)alloc((size_t)N * 256 * 2);
    unsigned short* hA  = (unsigned short*)alloc((size_t)N * 128 * 2);
    unsigned short* hB  = (unsigned short*)alloc((size_t)N * 128 * 2);

    const int* dstp = ei;       // edge_index row 0 = dst
    const int* srcp = ei + E;   // edge_index row 1 = src

    // CSR build (block-staged distribute -> per-bucket build w/ inline base scan)
    hipMemsetAsync(gcnt, 0, (size_t)NB * CPAD * 4, stream);
    int distBlocks = (E + EPB - 1) / EPB;   // 98
    distribute_kernel<<<distBlocks, 256, 0, stream>>>(dstp, srcp, gcnt, staging, E, NB);
    build_kernel<<<NB, 256, 0, stream>>>(staging, gcnt, row_ptr, adj, N, NB);

    // weight casts (x cast is fused into GEMM0)
    cast_w_kernel<<<160, 256, 0, stream>>>(Wl0, Wr0, Wl1, Wr1, Wl2, Wr2, wbf);
    unsigned short* wl0 = wbf;
    unsigned short* wr0 = wbf + 16384;
    unsigned short* wl1 = wbf + 32768;
    unsigned short* wr1 = wbf + 49152;
    unsigned short* wl2 = wbf + 65536;
    unsigned short* wr2 = wbf + 73728;

    dim3 blk(256);
    int gemmRows = (N + 63) / 64;       // 782 blocks, 64 rows each
    int aggBlocks = (N * 64 + 255) / 256;

    // Layer 0 (A = f32 x, cast in-kernel; x read exactly once)
    gemm_mfma_kernel<4, 1><<<gemmRows, blk, 0, stream>>>((const void*)x, wl0, wr0, C, N);
    agg_relu_kernel<<<aggBlocks, blk, 0, stream>>>(C, row_ptr, adj, bl0, hA, N);
    // Layer 1
    gemm_mfma_kernel<4, 0><<<gemmRows, blk, 0, stream>>>((const void*)hA, wl1, wr1, C, N);
    agg_relu_kernel<<<aggBlocks, blk, 0, stream>>>(C, row_ptr, adj, bl1, hB, N);
    // Layer 2 + log_softmax
    gemm_mfma_kernel<2, 0><<<gemmRows, blk, 0, stream>>>((const void*)hB, wl2, wr2, C, N);
    final_kernel<<<aggBlocks, blk, 0, stream>>>(C, row_ptr, adj, bl2, out, N);
}

// Round 5
// 270.044 us; speedup vs baseline: 1.0229x; 1.0229x over previous
//
#include <hip/hip_runtime.h>
#include <hip/hip_bf16.h>

// GraphSAGE 3-layer forward, MI355X. Round 10:
//  - GEMM: __launch_bounds__(256, 2). R9's full-tile prefetch was silently
//    defeated: VGPR_Count=88 proves the compiler sank the 32-load prefetch
//    (needs ~210 VGPR; acc alone is 64). Default occupancy heuristic capped
//    regs. (256,2) = 2 blocks/CU -> 256-VGPR cap -> prefetch can live.
//  - dispatch count 10 -> 8: cast_w fused into distribute (block-range
//    split, independent work); GEMM0 fused into build (independent: build
//    needs staging/gcnt, GEMM0 needs x+wl0 -- both ready after dist_cast).
//  - aggs/final/CSR logic unchanged.

typedef __attribute__((ext_vector_type(8))) short bf16x8;
typedef __attribute__((ext_vector_type(4))) float f32x4;

#define NPB 128            // nodes per bucket (bucket = dst >> 7)
#define BCAP 2560          // per-bucket staging capacity (mean 2048, sd ~45)
#define EPB 8192           // edges per distribute block
#define EPT 32             // edges per thread (256 thr)
#define CPAD 16            // global counter stride in ints (64B line each)

__device__ __forceinline__ unsigned short f2bf(float f) {
    unsigned int u = __builtin_bit_cast(unsigned int, f);
    u += 0x7fffu + ((u >> 16) & 1u);           // round-to-nearest-even
    return (unsigned short)(u >> 16);
}
__device__ __forceinline__ float bf2f(unsigned int bits16) {
    return __builtin_bit_cast(float, bits16 << 16);
}
__device__ __forceinline__ bf16x8 pack8(float4 lo, float4 hi) {
    bf16x8 r;
    r[0] = (short)f2bf(lo.x); r[1] = (short)f2bf(lo.y);
    r[2] = (short)f2bf(lo.z); r[3] = (short)f2bf(lo.w);
    r[4] = (short)f2bf(hi.x); r[5] = (short)f2bf(hi.y);
    r[6] = (short)f2bf(hi.z); r[7] = (short)f2bf(hi.w);
    return r;
}

// ---------------- distribute + weight-cast (fused, block-range split) ----------------
// staging word: dst << 16 | src (both < 65536). bucket = word >> 23 (= dst>>7).

__global__ __launch_bounds__(256) void dist_cast_kernel(const int* __restrict__ dst,
                                                        const int* __restrict__ srcv,
                                                        int* __restrict__ gcnt,
                                                        unsigned int* __restrict__ staging,
                                                        int E, int NBc, int DB,
                                                        const float* p0, const float* p1,
                                                        const float* p2, const float* p3,
                                                        const float* p4, const float* p5,
                                                        unsigned short* __restrict__ wbf) {
    __shared__ unsigned int stage[EPB];      // bucket-sorted edges (32KB)
    __shared__ int hist[400];                // histogram, then LDS cursor
    __shared__ int lstart[400];              // exclusive prefix (incl. sentinel bucket)
    __shared__ int gbase[400];               // reserved global base per bucket
    __shared__ int scanbuf[256];
    int bid = blockIdx.x;
    int t = threadIdx.x;

    if (bid >= DB) {                         // ---- weight cast part ----
        int w = (bid - DB) * 256 + t;
        if (w < 40960) {
            const float* src;
            int local;
            if      (w < 8192)  { src = p0; local = w; }
            else if (w < 16384) { src = p1; local = w - 8192; }
            else if (w < 24576) { src = p2; local = w - 16384; }
            else if (w < 32768) { src = p3; local = w - 24576; }
            else if (w < 36864) { src = p4; local = w - 32768; }
            else                { src = p5; local = w - 36864; }
            float2 v = ((const float2*)src)[local];
            unsigned int p = (unsigned int)f2bf(v.x) | ((unsigned int)f2bf(v.y) << 16);
            ((unsigned int*)wbf)[w] = p;
        }
        return;
    }

    // ---- distribute part ----
    int e0 = bid * EPB;
    unsigned int w[EPT];

    for (int b = t; b < NBc + 1; b += 256) hist[b] = 0;
    __syncthreads();

#pragma unroll
    for (int i = 0; i < EPT; ++i) {
        int e = e0 + i * 256 + t;            // coalesced
        unsigned int word = 0xFFFFFFFFu;     // sentinel -> bucket NBc
        if (e < E) word = ((unsigned int)dst[e] << 16) | (unsigned int)srcv[e];
        w[i] = word;
        int b = (int)(word >> 23); if (b > NBc) b = NBc;
        atomicAdd(&hist[b], 1);
    }
    __syncthreads();

    // exclusive scan over NBc+1 entries (2 per thread, Hillis-Steele on pairs)
    int b0 = 2 * t, b1 = 2 * t + 1;
    int h0 = (b0 <= NBc) ? hist[b0] : 0;
    int h1 = (b1 <= NBc) ? hist[b1] : 0;
    int pair = h0 + h1;
    scanbuf[t] = pair;
    __syncthreads();
    for (int off = 1; off < 256; off <<= 1) {
        int v = (t >= off) ? scanbuf[t - off] : 0;
        __syncthreads();
        scanbuf[t] += v;
        __syncthreads();
    }
    int excl = scanbuf[t] - pair;
    if (b0 <= NBc) lstart[b0] = excl;
    if (b1 <= NBc) lstart[b1] = excl + h0;
    __syncthreads();

    // one padded-line global atomic per non-empty bucket
    for (int b = t; b < NBc; b += 256) {
        int h = hist[b];
        gbase[b] = h ? atomicAdd(&gcnt[b * CPAD], h) : 0;
    }
    for (int b = t; b < NBc + 1; b += 256) hist[b] = lstart[b];   // -> LDS cursors
    __syncthreads();

#pragma unroll
    for (int i = 0; i < EPT; ++i) {
        unsigned int word = w[i];
        int b = (int)(word >> 23); if (b > NBc) b = NBc;
        int p = atomicAdd(&hist[b], 1);
        stage[p] = word;
    }
    __syncthreads();

    int total = lstart[NBc];                 // valid edges in this block
    for (int i = t; i < total; i += 256) {   // contiguous runs per bucket
        unsigned int word = stage[i];
        int b = (int)(word >> 23);
        int gpos = gbase[b] + (i - lstart[b]);
        staging[(size_t)b * BCAP + gpos] = word;
    }
}

// ---------------- GEMM body: full-tile register prefetch ----------------
// Block = 64 rows x (4*CF*16) cols; wave w owns col-group w (CF 16-col frags).
// All B (CF*4) and A (4*4) dwordx4 loads issue before any MFMA.
// AF32: A is f32 (layer 0, x); two rf-pair halves cap peak VGPR.

template<int CF, int AF32>
__device__ __forceinline__ void gemm_body(int mb,
                                          const void* __restrict__ Hp,
                                          const unsigned short* __restrict__ Wl,
                                          const unsigned short* __restrict__ Wr,
                                          unsigned short* __restrict__ C, int N) {
    int wave = threadIdx.x >> 6;
    int lane = threadIdx.x & 63;
    int l15 = lane & 15, quad = lane >> 4;
    const int NCOL = 4 * CF * 16;          // 256 (layers 0/1) or 128 (layer 2)
    const int half = NCOL >> 1;
    int m0 = mb * 64;

    // B fragments (loop-invariant, independent)
    bf16x8 bfr[CF][4];
#pragma unroll
    for (int cf = 0; cf < CF; ++cf) {
        int col0 = (wave * CF + cf) * 16;
        const unsigned short* W = (col0 < half) ? Wl : Wr;
        int wr = (col0 < half ? col0 : col0 - half) + l15;
#pragma unroll
        for (int ks = 0; ks < 4; ++ks)
            bfr[cf][ks] = ((const bf16x8*)(W + (size_t)wr * 128))[ks * 4 + quad];
    }

    f32x4 acc[4][CF] = {};

    if constexpr (AF32) {
        // two halves of the A tile (rf pairs), 16 f32x4 loads in flight each
#pragma unroll
        for (int h = 0; h < 2; ++h) {
            float4 fa[2][4][2];
#pragma unroll
            for (int p = 0; p < 2; ++p) {
                int rf = h * 2 + p;
                int r0 = m0 + rf * 16 + l15; if (r0 > N - 1) r0 = N - 1;
                const float4* A = (const float4*)((const float*)Hp + (size_t)r0 * 128);
#pragma unroll
                for (int ks = 0; ks < 4; ++ks) {
                    int vidx = ks * 4 + quad;
                    fa[p][ks][0] = A[vidx * 2];
                    fa[p][ks][1] = A[vidx * 2 + 1];
                }
            }
#pragma unroll
            for (int p = 0; p < 2; ++p) {
                int rf = h * 2 + p;
#pragma unroll
                for (int ks = 0; ks < 4; ++ks) {
                    bf16x8 a = pack8(fa[p][ks][0], fa[p][ks][1]);
#pragma unroll
                    for (int cf = 0; cf < CF; ++cf)
                        acc[rf][cf] = __builtin_amdgcn_mfma_f32_16x16x32_bf16(a, bfr[cf][ks],
                                                                              acc[rf][cf], 0, 0, 0);
                }
            }
        }
    } else {
        // full A tile prefetch: 16 independent dwordx4 loads
        bf16x8 afr[4][4];
#pragma unroll
        for (int rf = 0; rf < 4; ++rf) {
            int r0 = m0 + rf * 16 + l15; if (r0 > N - 1) r0 = N - 1;
            const bf16x8* A = (const bf16x8*)((const unsigned short*)Hp + (size_t)r0 * 128);
#pragma unroll
            for (int ks = 0; ks < 4; ++ks)
                afr[rf][ks] = A[ks * 4 + quad];
        }
#pragma unroll
        for (int rf = 0; rf < 4; ++rf)
#pragma unroll
            for (int ks = 0; ks < 4; ++ks)
#pragma unroll
                for (int cf = 0; cf < CF; ++cf)
                    acc[rf][cf] = __builtin_amdgcn_mfma_f32_16x16x32_bf16(afr[rf][ks], bfr[cf][ks],
                                                                          acc[rf][cf], 0, 0, 0);
    }

#pragma unroll
    for (int rf = 0; rf < 4; ++rf)
#pragma unroll
        for (int cf = 0; cf < CF; ++cf)
#pragma unroll
            for (int r = 0; r < 4; ++r) {
                int row = m0 + rf * 16 + quad * 4 + r;
                if (row < N)
                    C[(size_t)row * NCOL + (wave * CF + cf) * 16 + l15] = f2bf(acc[rf][cf][r]);
            }
}

// ---------------- build + GEMM0 (fused, block-range split) ----------------

template<int CF, int AF32>
__global__ __launch_bounds__(256, 2) void build_gemm_kernel(const unsigned int* __restrict__ staging,
                                                            const int* __restrict__ gcnt,
                                                            int* __restrict__ row_ptr,
                                                            int* __restrict__ adj, int N, int NBc,
                                                            const void* __restrict__ Hp,
                                                            const unsigned short* __restrict__ Wl,
                                                            const unsigned short* __restrict__ Wr,
                                                            unsigned short* __restrict__ C) {
    __shared__ int hist[NPB];   // histogram, then cursors
    __shared__ int scn[NPB];
    __shared__ int wsum[4];
    int bid = blockIdx.x;
    int t = threadIdx.x;

    if (bid >= NBc) {                        // ---- GEMM0 part ----
        gemm_body<CF, AF32>(bid - NBc, Hp, Wl, Wr, C, N);
        return;
    }

    // ---- build part ----
    int b = bid;
    int n0 = b * NPB;
    int nb = N - n0; if (nb > NPB) nb = NPB;
    int ec = gcnt[b * CPAD];
    const unsigned int* st = staging + (size_t)b * BCAP;

    // exclusive bucket base: sum of gcnt[0..b)
    int a = 0;
    for (int j = t; j < b; j += 256) a += gcnt[j * CPAD];
#pragma unroll
    for (int off = 32; off; off >>= 1) a += __shfl_xor(a, off);
    if ((t & 63) == 0) wsum[t >> 6] = a;
    if (t < NPB) hist[t] = 0;
    __syncthreads();
    int bb = wsum[0] + wsum[1] + wsum[2] + wsum[3];

    for (int i = t; i < ec; i += 256)
        atomicAdd(&hist[(st[i] >> 16) & (NPB - 1)], 1);
    __syncthreads();

    int v = (t < NPB) ? hist[t] : 0;
    if (t < NPB) scn[t] = v;
    __syncthreads();
    for (int off = 1; off < NPB; off <<= 1) {
        int u = (t >= off && t < NPB) ? scn[t - off] : 0;
        __syncthreads();
        if (t < NPB) scn[t] += u;
        __syncthreads();
    }
    if (t < NPB) hist[t] = scn[t] - v;      // exclusive prefix -> cursor base
    if (t < nb) row_ptr[n0 + t] = bb + (scn[t] - v);
    if (b == NBc - 1 && t == 0) row_ptr[N] = bb + ec;   // total == E
    __syncthreads();

    for (int i = t; i < ec; i += 256) {
        unsigned int pk = st[i];
        int p = atomicAdd(&hist[(pk >> 16) & (NPB - 1)], 1);
        adj[bb + p] = (int)(pk & 0xffffu);
    }
}

// ---------------- standalone GEMM (layers 1,2) ----------------

template<int CF, int AF32>
__global__ __launch_bounds__(256, 2) void gemm_mfma_kernel(const void* __restrict__ Hp,
                                                           const unsigned short* __restrict__ Wl,
                                                           const unsigned short* __restrict__ Wr,
                                                           unsigned short* __restrict__ C,
                                                           int N) {
    gemm_body<CF, AF32>(blockIdx.x, Hp, Wl, Wr, C, N);
}

// ---------------- Aggregation (layers 0,1): wave/node, vectorized 16B gathers ----
// lane = (g, c): g = lane>>4 edge slot (4 edges/round), c = lane&15 chunk
// (cols c*8..c*8+7). One dwordx4 load instruction = 4 rows x 256B = 1KB.

__global__ __launch_bounds__(256) void agg_relu_kernel(const unsigned short* __restrict__ C,
                                                       const int* __restrict__ row_ptr,
                                                       const int* __restrict__ adj,
                                                       const float* __restrict__ bias,
                                                       unsigned short* __restrict__ hout, int N) {
    int node = (int)((blockIdx.x * blockDim.x + threadIdx.x) >> 6);
    int lane = threadIdx.x & 63;
    if (node >= N) return;
    int g = lane >> 4;
    int c = lane & 15;
    int beg = row_ptr[node], end = row_ptr[node + 1];
    float p[8] = {};

    int e = beg;
    while (e < end) {
        int cnt = end - e; if (cnt > 64) cnt = 64;
        int ll = lane; if (ll > cnt - 1) ll = cnt - 1;
        int myidx = adj[e + ll];
        int c1 = cnt - 1;
        for (int i = 0; i < cnt; i += 16) {
            int t0 = i + g, t1 = i + 4 + g, t2 = i + 8 + g, t3 = i + 12 + g;
            int s0 = __shfl(myidx, t0 > c1 ? c1 : t0);
            int s1 = __shfl(myidx, t1 > c1 ? c1 : t1);
            int s2 = __shfl(myidx, t2 > c1 ? c1 : t2);
            int s3 = __shfl(myidx, t3 > c1 ? c1 : t3);
            float m0 = t0 < cnt ? 1.f : 0.f;
            float m1 = t1 < cnt ? 1.f : 0.f;
            float m2 = t2 < cnt ? 1.f : 0.f;
            float m3 = t3 < cnt ? 1.f : 0.f;
            bf16x8 v0 = ((const bf16x8*)(C + (size_t)s0 * 256))[c];
            bf16x8 v1 = ((const bf16x8*)(C + (size_t)s1 * 256))[c];
            bf16x8 v2 = ((const bf16x8*)(C + (size_t)s2 * 256))[c];
            bf16x8 v3 = ((const bf16x8*)(C + (size_t)s3 * 256))[c];
#pragma unroll
            for (int k = 0; k < 8; ++k) {
                p[k] += m0 * bf2f((unsigned short)v0[k]);
                p[k] += m1 * bf2f((unsigned short)v1[k]);
                p[k] += m2 * bf2f((unsigned short)v2[k]);
                p[k] += m3 * bf2f((unsigned short)v3[k]);
            }
        }
        e += cnt;
    }

    // reduce across the 4 edge-slot groups (lane bits 4,5)
#pragma unroll
    for (int k = 0; k < 8; ++k) {
        p[k] += __shfl_xor(p[k], 16);
        p[k] += __shfl_xor(p[k], 32);
    }

    int deg = end - beg;
    float inv = 1.0f / (float)(deg > 1 ? deg : 1);
    bf16x8 sv = ((const bf16x8*)(C + (size_t)node * 256))[16 + c];   // Wr self part
    float4 b0 = ((const float4*)bias)[2 * c];
    float4 b1 = ((const float4*)bias)[2 * c + 1];
    float bb[8] = {b0.x, b0.y, b0.z, b0.w, b1.x, b1.y, b1.z, b1.w};
    bf16x8 o;
#pragma unroll
    for (int k = 0; k < 8; ++k) {
        float v = fmaxf(p[k] * inv + bb[k] + bf2f((unsigned short)sv[k]), 0.f);
        o[k] = (short)f2bf(v);
    }
    if (g == 0)
        ((bf16x8*)(hout + (size_t)node * 128))[c] = o;
}

// ---------------- Final layer: vectorized gathers + fused log_softmax ----------------
// lane = (g, c): g = lane>>3 edge slot (8 edges/round), c = lane&7 chunk
// (cols c*8..c*8+7). Row = 64 cols bf16 = 128B = 8 chunks.

__global__ __launch_bounds__(256) void final_kernel(const unsigned short* __restrict__ C,
                                                    const int* __restrict__ row_ptr,
                                                    const int* __restrict__ adj,
                                                    const float* __restrict__ bias,
                                                    float* __restrict__ out, int N) {
    int node = (int)((blockIdx.x * blockDim.x + threadIdx.x) >> 6);
    int lane = threadIdx.x & 63;
    if (node >= N) return;
    int g = lane >> 3;
    int c = lane & 7;
    int beg = row_ptr[node], end = row_ptr[node + 1];
    float p[8] = {};

    int e = beg;
    while (e < end) {
        int cnt = end - e; if (cnt > 64) cnt = 64;
        int ll = lane; if (ll > cnt - 1) ll = cnt - 1;
        int myidx = adj[e + ll];
        int c1 = cnt - 1;
        for (int i = 0; i < cnt; i += 16) {
            int ta = i + g, tb = i + 8 + g;
            int sa = __shfl(myidx, ta > c1 ? c1 : ta);
            int sb = __shfl(myidx, tb > c1 ? c1 : tb);
            float ma = ta < cnt ? 1.f : 0.f;
            float mb = tb < cnt ? 1.f : 0.f;
            bf16x8 va = ((const bf16x8*)(C + (size_t)sa * 128))[c];
            bf16x8 vb = ((const bf16x8*)(C + (size_t)sb * 128))[c];
#pragma unroll
            for (int k = 0; k < 8; ++k) {
                p[k] += ma * bf2f((unsigned short)va[k]);
                p[k] += mb * bf2f((unsigned short)vb[k]);
            }
        }
        e += cnt;
    }

    // reduce across the 8 edge-slot groups (lane bits 3,4,5)
#pragma unroll
    for (int k = 0; k < 8; ++k) {
        p[k] += __shfl_xor(p[k], 8);
        p[k] += __shfl_xor(p[k], 16);
        p[k] += __shfl_xor(p[k], 32);
    }

    int deg = end - beg;
    float inv = 1.0f / (float)(deg > 1 ? deg : 1);
    bf16x8 sv = ((const bf16x8*)(C + (size_t)node * 128))[8 + c];    // Wr self part
    float4 b0 = ((const float4*)bias)[2 * c];
    float4 b1 = ((const float4*)bias)[2 * c + 1];
    float bb[8] = {b0.x, b0.y, b0.z, b0.w, b1.x, b1.y, b1.z, b1.w};
    float u[8];
#pragma unroll
    for (int k = 0; k < 8; ++k)
        u[k] = p[k] * inv + bb[k] + bf2f((unsigned short)sv[k]);

    // log_softmax over the 64 cols: per-lane max/sum over 8, then across c
    float m = u[0];
#pragma unroll
    for (int k = 1; k < 8; ++k) m = fmaxf(m, u[k]);
#pragma unroll
    for (int off = 1; off < 8; off <<= 1) m = fmaxf(m, __shfl_xor(m, off));
    float se = 0.f;
#pragma unroll
    for (int k = 0; k < 8; ++k) se += __expf(u[k] - m);
#pragma unroll
    for (int off = 1; off < 8; off <<= 1) se += __shfl_xor(se, off);
    float ls = __logf(se);

    if (g == 0) {
        float4 o0 = {u[0] - m - ls, u[1] - m - ls, u[2] - m - ls, u[3] - m - ls};
        float4 o1 = {u[4] - m - ls, u[5] - m - ls, u[6] - m - ls, u[7] - m - ls};
        ((float4*)(out + (size_t)node * 64))[2 * c] = o0;
        ((float4*)(out + (size_t)node * 64))[2 * c + 1] = o1;
    }
}

// ---------------- Launch ----------------

extern "C" void kernel_launch(void* const* d_in, const int* in_sizes, int n_in,
                              void* d_out, int out_size, void* d_ws, size_t ws_size,
                              hipStream_t stream) {
    const float* x   = (const float*)d_in[0];
    const int*   ei  = (const int*)d_in[1];
    const float* Wl0 = (const float*)d_in[2];
    const float* bl0 = (const float*)d_in[3];
    const float* Wr0 = (const float*)d_in[4];
    const float* Wl1 = (const float*)d_in[5];
    const float* bl1 = (const float*)d_in[6];
    const float* Wr1 = (const float*)d_in[7];
    const float* Wl2 = (const float*)d_in[8];
    const float* bl2 = (const float*)d_in[9];
    const float* Wr2 = (const float*)d_in[10];
    float* out = (float*)d_out;

    const int N  = in_sizes[0] / 128;   // 50000
    const int E  = in_sizes[1] / 2;     // 800000
    const int NB = (N + NPB - 1) / NPB; // 391 buckets

    char* ws = (char*)d_ws;
    auto alloc = [&](size_t bytes) {
        char* p = ws;
        ws += (bytes + 255) & ~(size_t)255;
        return p;
    };
    int*   row_ptr    = (int*)alloc((size_t)(N + 1) * 4);
    int*   adj        = (int*)alloc((size_t)E * 4);
    int*   gcnt       = (int*)alloc((size_t)NB * CPAD * 4);  // 64B-padded counters
    unsigned int* staging = (unsigned int*)alloc((size_t)NB * BCAP * 4);
    unsigned short* wbf = (unsigned short*)alloc((size_t)81920 * 2);
    unsigned short* C   = (unsigned short*)alloc((size_t)N * 256 * 2);
    unsigned short* hA  = (unsigned short*)alloc((size_t)N * 128 * 2);
    unsigned short* hB  = (unsigned short*)alloc((size_t)N * 128 * 2);

    const int* dstp = ei;       // edge_index row 0 = dst
    const int* srcp = ei + E;   // edge_index row 1 = src

    unsigned short* wl0 = wbf;
    unsigned short* wr0 = wbf + 16384;
    unsigned short* wl1 = wbf + 32768;
    unsigned short* wr1 = wbf + 49152;
    unsigned short* wl2 = wbf + 65536;
    unsigned short* wr2 = wbf + 73728;

    dim3 blk(256);
    int DB = (E + EPB - 1) / EPB;       // 98 distribute blocks
    int gemmRows = (N + 63) / 64;       // 782 GEMM blocks, 64 rows each
    int aggBlocks = (N * 64 + 255) / 256;

    // 1) zero bucket counters
    hipMemsetAsync(gcnt, 0, (size_t)NB * CPAD * 4, stream);
    // 2) distribute + weight cast (fused)
    dist_cast_kernel<<<DB + 160, blk, 0, stream>>>(dstp, srcp, gcnt, staging, E, NB, DB,
                                                   Wl0, Wr0, Wl1, Wr1, Wl2, Wr2, wbf);
    // 3) build + GEMM0 (fused; A = f32 x, cast in-kernel)
    build_gemm_kernel<4, 1><<<NB + gemmRows, blk, 0, stream>>>(staging, gcnt, row_ptr, adj,
                                                               N, NB, (const void*)x, wl0, wr0, C);
    // 4) agg0
    agg_relu_kernel<<<aggBlocks, blk, 0, stream>>>(C, row_ptr, adj, bl0, hA, N);
    // 5) GEMM1
    gemm_mfma_kernel<4, 0><<<gemmRows, blk, 0, stream>>>((const void*)hA, wl1, wr1, C, N);
    // 6) agg1
    agg_relu_kernel<<<aggBlocks, blk, 0, stream>>>(C, row_ptr, adj, bl1, hB, N);
    // 7) GEMM2
    gemm_mfma_kernel<2, 0><<<gemmRows, blk, 0, stream>>>((const void*)hB, wl2, wr2, C, N);
    // 8) final + log_softmax
    final_kernel<<<aggBlocks, blk, 0, stream>>>(C, row_ptr, adj, bl2, out, N);
}

// Round 6
// 267.930 us; speedup vs baseline: 1.0309x; 1.0079x over previous
//
#include <hip/hip_runtime.h>
#include <hip/hip_bf16.h>

// GraphSAGE 3-layer forward, MI355X. Round 11:
//  - GEMM reverted to R5 light geometry (128-row x 64-col y-split blocks,
//    2x4 frags/wave, in-loop B loads, ~75 VGPR -> high occupancy). R7-R10's
//    register-heavy all-cols designs were all 35-48us at 2.4% MfmaUtil /
//    <25% occupancy; R5/R6 evidence shows light bf16 y-split ran 20-25us.
//    TLP > ILP for this skinny GEMM.
//  - x f32->bf16 cast restored (fused into dist_cast as extra blocks, 4-deep
//    float2 grid-stride): all GEMMs read bf16 A (R6 proved f32-A 4x re-read
//    costs ~20us).
//  - NEW: coalesced C-store epilogue. Old: 64 scattered 2B stores/thread
//    (4x32B segments per instr). Now: per-wave LDS transpose (32x68 ushort,
//    stride 136B: write conflict-free, ~4-way read) -> 8 dense dwordx4
//    stores/thread on 128B segments.
//  - build+GEMM0 fusion, vectorized aggs, CSR build unchanged.

typedef __attribute__((ext_vector_type(8))) short bf16x8;
typedef __attribute__((ext_vector_type(4))) float f32x4;

#define NPB 128            // nodes per bucket (bucket = dst >> 7)
#define BCAP 2560          // per-bucket staging capacity (mean 2048, sd ~45)
#define EPB 8192           // edges per distribute block
#define EPT 32             // edges per thread (256 thr)
#define CPAD 16            // global counter stride in ints (64B line each)

__device__ __forceinline__ unsigned short f2bf(float f) {
    unsigned int u = __builtin_bit_cast(unsigned int, f);
    u += 0x7fffu + ((u >> 16) & 1u);           // round-to-nearest-even
    return (unsigned short)(u >> 16);
}
__device__ __forceinline__ float bf2f(unsigned int bits16) {
    return __builtin_bit_cast(float, bits16 << 16);
}

// ---------------- distribute + x-cast + weight-cast (fused, block ranges) --------
// staging word: dst << 16 | src (both < 65536). bucket = word >> 23 (= dst>>7).
// ranges: [0,DB) distribute | [DB,DB+XB) x-cast (4-deep) | [DB+XB,+160) weights.

__global__ __launch_bounds__(256) void dist_cast_kernel(const int* __restrict__ dst,
                                                        const int* __restrict__ srcv,
                                                        int* __restrict__ gcnt,
                                                        unsigned int* __restrict__ staging,
                                                        int E, int NBc, int DB, int XB,
                                                        const float* __restrict__ x,
                                                        unsigned short* __restrict__ xbf,
                                                        const float* p0, const float* p1,
                                                        const float* p2, const float* p3,
                                                        const float* p4, const float* p5,
                                                        unsigned short* __restrict__ wbf) {
    __shared__ unsigned int stage[EPB];      // bucket-sorted edges (32KB)
    __shared__ int hist[400];                // histogram, then LDS cursor
    __shared__ int lstart[400];              // exclusive prefix (incl. sentinel bucket)
    __shared__ int gbase[400];               // reserved global base per bucket
    __shared__ int scanbuf[256];
    int bid = blockIdx.x;
    int t = threadIdx.x;

    if (bid >= DB && bid < DB + XB) {        // ---- x cast: 4 float2 per thread ----
        int base = (bid - DB) * 256 + t;
        int stride = XB * 256;               // 800000, 4*stride == N*64 exactly
        const float2* x2 = (const float2*)x;
        unsigned int* xo = (unsigned int*)xbf;
#pragma unroll
        for (int k = 0; k < 4; ++k) {
            int idx = base + k * stride;
            float2 v = x2[idx];
            xo[idx] = (unsigned int)f2bf(v.x) | ((unsigned int)f2bf(v.y) << 16);
        }
        return;
    }
    if (bid >= DB + XB) {                    // ---- weight cast part ----
        int w = (bid - DB - XB) * 256 + t;
        if (w < 40960) {
            const float* src;
            int local;
            if      (w < 8192)  { src = p0; local = w; }
            else if (w < 16384) { src = p1; local = w - 8192; }
            else if (w < 24576) { src = p2; local = w - 16384; }
            else if (w < 32768) { src = p3; local = w - 24576; }
            else if (w < 36864) { src = p4; local = w - 32768; }
            else                { src = p5; local = w - 36864; }
            float2 v = ((const float2*)src)[local];
            unsigned int p = (unsigned int)f2bf(v.x) | ((unsigned int)f2bf(v.y) << 16);
            ((unsigned int*)wbf)[w] = p;
        }
        return;
    }

    // ---- distribute part ----
    int e0 = bid * EPB;
    unsigned int w[EPT];

    for (int b = t; b < NBc + 1; b += 256) hist[b] = 0;
    __syncthreads();

#pragma unroll
    for (int i = 0; i < EPT; ++i) {
        int e = e0 + i * 256 + t;            // coalesced
        unsigned int word = 0xFFFFFFFFu;     // sentinel -> bucket NBc
        if (e < E) word = ((unsigned int)dst[e] << 16) | (unsigned int)srcv[e];
        w[i] = word;
        int b = (int)(word >> 23); if (b > NBc) b = NBc;
        atomicAdd(&hist[b], 1);
    }
    __syncthreads();

    // exclusive scan over NBc+1 entries (2 per thread, Hillis-Steele on pairs)
    int b0 = 2 * t, b1 = 2 * t + 1;
    int h0 = (b0 <= NBc) ? hist[b0] : 0;
    int h1 = (b1 <= NBc) ? hist[b1] : 0;
    int pair = h0 + h1;
    scanbuf[t] = pair;
    __syncthreads();
    for (int off = 1; off < 256; off <<= 1) {
        int v = (t >= off) ? scanbuf[t - off] : 0;
        __syncthreads();
        scanbuf[t] += v;
        __syncthreads();
    }
    int excl = scanbuf[t] - pair;
    if (b0 <= NBc) lstart[b0] = excl;
    if (b1 <= NBc) lstart[b1] = excl + h0;
    __syncthreads();

    // one padded-line global atomic per non-empty bucket
    for (int b = t; b < NBc; b += 256) {
        int h = hist[b];
        gbase[b] = h ? atomicAdd(&gcnt[b * CPAD], h) : 0;
    }
    for (int b = t; b < NBc + 1; b += 256) hist[b] = lstart[b];   // -> LDS cursors
    __syncthreads();

#pragma unroll
    for (int i = 0; i < EPT; ++i) {
        unsigned int word = w[i];
        int b = (int)(word >> 23); if (b > NBc) b = NBc;
        int p = atomicAdd(&hist[b], 1);
        stage[p] = word;
    }
    __syncthreads();

    int total = lstart[NBc];                 // valid edges in this block
    for (int i = t; i < total; i += 256) {   // contiguous runs per bucket
        unsigned int word = stage[i];
        int b = (int)(word >> 23);
        int gpos = gbase[b] + (i - lstart[b]);
        staging[(size_t)b * BCAP + gpos] = word;
    }
}

// ---------------- GEMM body: R5 light geometry + coalesced LDS epilogue --------
// Block = 128 rows (4 waves x 32) x 64 cols (col-group y of GY). Wave: 2 row-
// frags x 4 col-frags, in-loop B loads (L2-hot), acc 32 VGPR. Epilogue stages
// the wave's 32x64 tile in LDS (stride 68 ushort = 136B) then writes 4
// dwordx4 passes, fully coalesced 128B segments.

template<int GY>
__device__ __forceinline__ void gemm_body(int mb, int y,
                                          const unsigned short* __restrict__ H,
                                          const unsigned short* __restrict__ Wl,
                                          const unsigned short* __restrict__ Wr,
                                          unsigned short* __restrict__ C, int N) {
    __shared__ unsigned short clds[4 * 32 * 68];   // 17408 B
    const int NCOL = GY * 64;
    const int half = GY >> 1;
    int wave = threadIdx.x >> 6;
    int lane = threadIdx.x & 63;
    int l15 = lane & 15, quad = lane >> 4;
    const unsigned short* W = (y < half) ? Wl : Wr;
    int wrow0 = (y < half ? y : y - half) * 64;
    int col0 = y * 64;
    int m0 = mb * 128 + wave * 32;

    int r0 = m0 + l15;      if (r0 > N - 1) r0 = N - 1;
    int r1 = m0 + 16 + l15; if (r1 > N - 1) r1 = N - 1;
    const bf16x8* A0 = (const bf16x8*)(H + (size_t)r0 * 128);
    const bf16x8* A1 = (const bf16x8*)(H + (size_t)r1 * 128);

    f32x4 acc[2][4] = {};
#pragma unroll
    for (int ks = 0; ks < 4; ++ks) {
        int vidx = ks * 4 + quad;
        bf16x8 a0 = A0[vidx];
        bf16x8 a1 = A1[vidx];
#pragma unroll
        for (int j = 0; j < 4; ++j) {
            const bf16x8* B = (const bf16x8*)(W + (size_t)(wrow0 + j * 16 + l15) * 128);
            bf16x8 b = B[vidx];
            acc[0][j] = __builtin_amdgcn_mfma_f32_16x16x32_bf16(a0, b, acc[0][j], 0, 0, 0);
            acc[1][j] = __builtin_amdgcn_mfma_f32_16x16x32_bf16(a1, b, acc[1][j], 0, 0, 0);
        }
    }

    // stage to LDS: row_local = i*16+quad*4+r (0..31), col_local = j*16+l15
    unsigned short* slice = clds + wave * (32 * 68);
#pragma unroll
    for (int i = 0; i < 2; ++i)
#pragma unroll
        for (int j = 0; j < 4; ++j)
#pragma unroll
            for (int r = 0; r < 4; ++r)
                slice[(i * 16 + quad * 4 + r) * 68 + j * 16 + l15] = f2bf(acc[i][j][r]);
    __syncthreads();

    // read back 8 rows/pass x 16B/lane, store coalesced dwordx4
    int rlo = lane >> 3, j8 = lane & 7;
#pragma unroll
    for (int pass = 0; pass < 4; ++pass) {
        int row_local = pass * 8 + rlo;
        const unsigned short* p = slice + row_local * 68 + j8 * 8;
        unsigned long long lo = *(const unsigned long long*)(p);
        unsigned long long hi = *(const unsigned long long*)(p + 4);
        int row = m0 + row_local;
        if (row < N) {
            unsigned long long* q = (unsigned long long*)(C + (size_t)row * NCOL + col0 + j8 * 8);
            q[0] = lo;
            q[1] = hi;
        }
    }
}

// ---------------- build + GEMM0 (fused, block-range split) ----------------

__global__ __launch_bounds__(256) void build_gemm_kernel(const unsigned int* __restrict__ staging,
                                                         const int* __restrict__ gcnt,
                                                         int* __restrict__ row_ptr,
                                                         int* __restrict__ adj, int N, int NBc,
                                                         int gemmRows,
                                                         const unsigned short* __restrict__ H,
                                                         const unsigned short* __restrict__ Wl,
                                                         const unsigned short* __restrict__ Wr,
                                                         unsigned short* __restrict__ C) {
    __shared__ int hist[NPB];   // histogram, then cursors
    __shared__ int scn[NPB];
    __shared__ int wsum[4];
    int bid = blockIdx.x;
    int t = threadIdx.x;

    if (bid >= NBc) {                        // ---- GEMM0 part ----
        int gid = bid - NBc;
        int mb = gid % gemmRows;
        int yy = gid / gemmRows;
        gemm_body<4>(mb, yy, H, Wl, Wr, C, N);
        return;
    }

    // ---- build part ----
    int b = bid;
    int n0 = b * NPB;
    int nb = N - n0; if (nb > NPB) nb = NPB;
    int ec = gcnt[b * CPAD];
    const unsigned int* st = staging + (size_t)b * BCAP;

    // exclusive bucket base: sum of gcnt[0..b)
    int a = 0;
    for (int j = t; j < b; j += 256) a += gcnt[j * CPAD];
#pragma unroll
    for (int off = 32; off; off >>= 1) a += __shfl_xor(a, off);
    if ((t & 63) == 0) wsum[t >> 6] = a;
    if (t < NPB) hist[t] = 0;
    __syncthreads();
    int bb = wsum[0] + wsum[1] + wsum[2] + wsum[3];

    for (int i = t; i < ec; i += 256)
        atomicAdd(&hist[(st[i] >> 16) & (NPB - 1)], 1);
    __syncthreads();

    int v = (t < NPB) ? hist[t] : 0;
    if (t < NPB) scn[t] = v;
    __syncthreads();
    for (int off = 1; off < NPB; off <<= 1) {
        int u = (t >= off && t < NPB) ? scn[t - off] : 0;
        __syncthreads();
        if (t < NPB) scn[t] += u;
        __syncthreads();
    }
    if (t < NPB) hist[t] = scn[t] - v;      // exclusive prefix -> cursor base
    if (t < nb) row_ptr[n0 + t] = bb + (scn[t] - v);
    if (b == NBc - 1 && t == 0) row_ptr[N] = bb + ec;   // total == E
    __syncthreads();

    for (int i = t; i < ec; i += 256) {
        unsigned int pk = st[i];
        int p = atomicAdd(&hist[(pk >> 16) & (NPB - 1)], 1);
        adj[bb + p] = (int)(pk & 0xffffu);
    }
}

// ---------------- standalone GEMM (layers 1,2) ----------------

template<int GY>
__global__ __launch_bounds__(256) void gemm_mfma_kernel(const unsigned short* __restrict__ H,
                                                        const unsigned short* __restrict__ Wl,
                                                        const unsigned short* __restrict__ Wr,
                                                        unsigned short* __restrict__ C,
                                                        int N) {
    gemm_body<GY>(blockIdx.x, blockIdx.y, H, Wl, Wr, C, N);
}

// ---------------- Aggregation (layers 0,1): wave/node, vectorized 16B gathers ----
// lane = (g, c): g = lane>>4 edge slot (4 edges/round), c = lane&15 chunk
// (cols c*8..c*8+7). One dwordx4 load instruction = 4 rows x 256B = 1KB.

__global__ __launch_bounds__(256) void agg_relu_kernel(const unsigned short* __restrict__ C,
                                                       const int* __restrict__ row_ptr,
                                                       const int* __restrict__ adj,
                                                       const float* __restrict__ bias,
                                                       unsigned short* __restrict__ hout, int N) {
    int node = (int)((blockIdx.x * blockDim.x + threadIdx.x) >> 6);
    int lane = threadIdx.x & 63;
    if (node >= N) return;
    int g = lane >> 4;
    int c = lane & 15;
    int beg = row_ptr[node], end = row_ptr[node + 1];
    float p[8] = {};

    int e = beg;
    while (e < end) {
        int cnt = end - e; if (cnt > 64) cnt = 64;
        int ll = lane; if (ll > cnt - 1) ll = cnt - 1;
        int myidx = adj[e + ll];
        int c1 = cnt - 1;
        for (int i = 0; i < cnt; i += 16) {
            int t0 = i + g, t1 = i + 4 + g, t2 = i + 8 + g, t3 = i + 12 + g;
            int s0 = __shfl(myidx, t0 > c1 ? c1 : t0);
            int s1 = __shfl(myidx, t1 > c1 ? c1 : t1);
            int s2 = __shfl(myidx, t2 > c1 ? c1 : t2);
            int s3 = __shfl(myidx, t3 > c1 ? c1 : t3);
            float m0 = t0 < cnt ? 1.f : 0.f;
            float m1 = t1 < cnt ? 1.f : 0.f;
            float m2 = t2 < cnt ? 1.f : 0.f;
            float m3 = t3 < cnt ? 1.f : 0.f;
            bf16x8 v0 = ((const bf16x8*)(C + (size_t)s0 * 256))[c];
            bf16x8 v1 = ((const bf16x8*)(C + (size_t)s1 * 256))[c];
            bf16x8 v2 = ((const bf16x8*)(C + (size_t)s2 * 256))[c];
            bf16x8 v3 = ((const bf16x8*)(C + (size_t)s3 * 256))[c];
#pragma unroll
            for (int k = 0; k < 8; ++k) {
                p[k] += m0 * bf2f((unsigned short)v0[k]);
                p[k] += m1 * bf2f((unsigned short)v1[k]);
                p[k] += m2 * bf2f((unsigned short)v2[k]);
                p[k] += m3 * bf2f((unsigned short)v3[k]);
            }
        }
        e += cnt;
    }

    // reduce across the 4 edge-slot groups (lane bits 4,5)
#pragma unroll
    for (int k = 0; k < 8; ++k) {
        p[k] += __shfl_xor(p[k], 16);
        p[k] += __shfl_xor(p[k], 32);
    }

    int deg = end - beg;
    float inv = 1.0f / (float)(deg > 1 ? deg : 1);
    bf16x8 sv = ((const bf16x8*)(C + (size_t)node * 256))[16 + c];   // Wr self part
    float4 b0 = ((const float4*)bias)[2 * c];
    float4 b1 = ((const float4*)bias)[2 * c + 1];
    float bb[8] = {b0.x, b0.y, b0.z, b0.w, b1.x, b1.y, b1.z, b1.w};
    bf16x8 o;
#pragma unroll
    for (int k = 0; k < 8; ++k) {
        float v = fmaxf(p[k] * inv + bb[k] + bf2f((unsigned short)sv[k]), 0.f);
        o[k] = (short)f2bf(v);
    }
    if (g == 0)
        ((bf16x8*)(hout + (size_t)node * 128))[c] = o;
}

// ---------------- Final layer: vectorized gathers + fused log_softmax ----------------
// lane = (g, c): g = lane>>3 edge slot (8 edges/round), c = lane&7 chunk
// (cols c*8..c*8+7). Row = 64 cols bf16 = 128B = 8 chunks.

__global__ __launch_bounds__(256) void final_kernel(const unsigned short* __restrict__ C,
                                                    const int* __restrict__ row_ptr,
                                                    const int* __restrict__ adj,
                                                    const float* __restrict__ bias,
                                                    float* __restrict__ out, int N) {
    int node = (int)((blockIdx.x * blockDim.x + threadIdx.x) >> 6);
    int lane = threadIdx.x & 63;
    if (node >= N) return;
    int g = lane >> 3;
    int c = lane & 7;
    int beg = row_ptr[node], end = row_ptr[node + 1];
    float p[8] = {};

    int e = beg;
    while (e < end) {
        int cnt = end - e; if (cnt > 64) cnt = 64;
        int ll = lane; if (ll > cnt - 1) ll = cnt - 1;
        int myidx = adj[e + ll];
        int c1 = cnt - 1;
        for (int i = 0; i < cnt; i += 16) {
            int ta = i + g, tb = i + 8 + g;
            int sa = __shfl(myidx, ta > c1 ? c1 : ta);
            int sb = __shfl(myidx, tb > c1 ? c1 : tb);
            float ma = ta < cnt ? 1.f : 0.f;
            float mb = tb < cnt ? 1.f : 0.f;
            bf16x8 va = ((const bf16x8*)(C + (size_t)sa * 128))[c];
            bf16x8 vb = ((const bf16x8*)(C + (size_t)sb * 128))[c];
#pragma unroll
            for (int k = 0; k < 8; ++k) {
                p[k] += ma * bf2f((unsigned short)va[k]);
                p[k] += mb * bf2f((unsigned short)vb[k]);
            }
        }
        e += cnt;
    }

    // reduce across the 8 edge-slot groups (lane bits 3,4,5)
#pragma unroll
    for (int k = 0; k < 8; ++k) {
        p[k] += __shfl_xor(p[k], 8);
        p[k] += __shfl_xor(p[k], 16);
        p[k] += __shfl_xor(p[k], 32);
    }

    int deg = end - beg;
    float inv = 1.0f / (float)(deg > 1 ? deg : 1);
    bf16x8 sv = ((const bf16x8*)(C + (size_t)node * 128))[8 + c];    // Wr self part
    float4 b0 = ((const float4*)bias)[2 * c];
    float4 b1 = ((const float4*)bias)[2 * c + 1];
    float bb[8] = {b0.x, b0.y, b0.z, b0.w, b1.x, b1.y, b1.z, b1.w};
    float u[8];
#pragma unroll
    for (int k = 0; k < 8; ++k)
        u[k] = p[k] * inv + bb[k] + bf2f((unsigned short)sv[k]);

    // log_softmax over the 64 cols: per-lane max/sum over 8, then across c
    float m = u[0];
#pragma unroll
    for (int k = 1; k < 8; ++k) m = fmaxf(m, u[k]);
#pragma unroll
    for (int off = 1; off < 8; off <<= 1) m = fmaxf(m, __shfl_xor(m, off));
    float se = 0.f;
#pragma unroll
    for (int k = 0; k < 8; ++k) se += __expf(u[k] - m);
#pragma unroll
    for (int off = 1; off < 8; off <<= 1) se += __shfl_xor(se, off);
    float ls = __logf(se);

    if (g == 0) {
        float4 o0 = {u[0] - m - ls, u[1] - m - ls, u[2] - m - ls, u[3] - m - ls};
        float4 o1 = {u[4] - m - ls, u[5] - m - ls, u[6] - m - ls, u[7] - m - ls};
        ((float4*)(out + (size_t)node * 64))[2 * c] = o0;
        ((float4*)(out + (size_t)node * 64))[2 * c + 1] = o1;
    }
}

// ---------------- Launch ----------------

extern "C" void kernel_launch(void* const* d_in, const int* in_sizes, int n_in,
                              void* d_out, int out_size, void* d_ws, size_t ws_size,
                              hipStream_t stream) {
    const float* x   = (const float*)d_in[0];
    const int*   ei  = (const int*)d_in[1];
    const float* Wl0 = (const float*)d_in[2];
    const float* bl0 = (const float*)d_in[3];
    const float* Wr0 = (const float*)d_in[4];
    const float* Wl1 = (const float*)d_in[5];
    const float* bl1 = (const float*)d_in[6];
    const float* Wr1 = (const float*)d_in[7];
    const float* Wl2 = (const float*)d_in[8];
    const float* bl2 = (const float*)d_in[9];
    const float* Wr2 = (const float*)d_in[10];
    float* out = (float*)d_out;

    const int N  = in_sizes[0] / 128;   // 50000
    const int E  = in_sizes[1] / 2;     // 800000
    const int NB = (N + NPB - 1) / NPB; // 391 buckets

    char* ws = (char*)d_ws;
    auto alloc = [&](size_t bytes) {
        char* p = ws;
        ws += (bytes + 255) & ~(size_t)255;
        return p;
    };
    int*   row_ptr    = (int*)alloc((size_t)(N + 1) * 4);
    int*   adj        = (int*)alloc((size_t)E * 4);
    int*   gcnt       = (int*)alloc((size_t)NB * CPAD * 4);  // 64B-padded counters
    unsigned int* staging = (unsigned int*)alloc((size_t)NB * BCAP * 4);
    unsigned short* xbf = (unsigned short*)alloc((size_t)N * 128 * 2);
    unsigned short* wbf = (unsigned short*)alloc((size_t)81920 * 2);
    unsigned short* C   = (unsigned short*)alloc((size_t)N * 256 * 2);
    unsigned short* hA  = (unsigned short*)alloc((size_t)N * 128 * 2);
    unsigned short* hB  = (unsigned short*)alloc((size_t)N * 128 * 2);

    const int* dstp = ei;       // edge_index row 0 = dst
    const int* srcp = ei + E;   // edge_index row 1 = src

    unsigned short* wl0 = wbf;
    unsigned short* wr0 = wbf + 16384;
    unsigned short* wl1 = wbf + 32768;
    unsigned short* wr1 = wbf + 49152;
    unsigned short* wl2 = wbf + 65536;
    unsigned short* wr2 = wbf + 73728;

    dim3 blk(256);
    int DB = (E + EPB - 1) / EPB;       // 98 distribute blocks
    int XB = (N * 64) / (256 * 4);      // 3125 x-cast blocks (4 float2/thread)
    int gemmRows = (N + 127) / 128;     // 391 row-blocks of 128
    int aggBlocks = (N * 64 + 255) / 256;

    // 1) zero bucket counters
    hipMemsetAsync(gcnt, 0, (size_t)NB * CPAD * 4, stream);
    // 2) distribute + x cast + weight cast (fused)
    dist_cast_kernel<<<DB + XB + 160, blk, 0, stream>>>(dstp, srcp, gcnt, staging, E, NB,
                                                        DB, XB, x, xbf,
                                                        Wl0, Wr0, Wl1, Wr1, Wl2, Wr2, wbf);
    // 3) build + GEMM0 (fused; bf16 A)
    build_gemm_kernel<<<NB + gemmRows * 4, blk, 0, stream>>>(staging, gcnt, row_ptr, adj,
                                                             N, NB, gemmRows, xbf, wl0, wr0, C);
    // 4) agg0
    agg_relu_kernel<<<aggBlocks, blk, 0, stream>>>(C, row_ptr, adj, bl0, hA, N);
    // 5) GEMM1
    gemm_mfma_kernel<4><<<dim3(gemmRows, 4), blk, 0, stream>>>(hA, wl1, wr1, C, N);
    // 6) agg1
    agg_relu_kernel<<<aggBlocks, blk, 0, stream>>>(C, row_ptr, adj, bl1, hB, N);
    // 7) GEMM2
    gemm_mfma_kernel<2><<<dim3(gemmRows, 2), blk, 0, stream>>>(hB, wl2, wr2, C, N);
    // 8) final + log_softmax
    final_kernel<<<aggBlocks, blk, 0, stream>>>(C, row_ptr, adj, bl2, out, N);
}